// Round 1
// baseline (324.958 us; speedup 1.0000x reference)
//
#include <hip/hip_runtime.h>
#include <hip/hip_fp16.h>

typedef _Float16 half8 __attribute__((ext_vector_type(8)));
typedef _Float16 half4 __attribute__((ext_vector_type(4)));
typedef _Float16 half2v __attribute__((ext_vector_type(2)));
typedef float f32x4 __attribute__((ext_vector_type(4)));

#define SEQ   2048
#define DM    1024
#define NH    16
#define HD    64
#define BSZ   4
#define BH_N  (BSZ*NH)

// async global->LDS, 16B per lane. LDS dest = wave-uniform base + lane*16.
__device__ __forceinline__ void gload16(const void* g, void* l) {
  __builtin_amdgcn_global_load_lds((const __attribute__((address_space(1))) void*)g,
                                   (__attribute__((address_space(3))) void*)l,
                                   16, 0, 0);
}

// ---------------- fp32 -> fp16 convert (vectorized) ----------------
__global__ void cvt4(const float* __restrict__ src, _Float16* __restrict__ dst, int n4) {
  int i = blockIdx.x * blockDim.x + threadIdx.x;
  if (i < n4) {
    float4 v = ((const float4*)src)[i];
    half4 o = { (_Float16)v.x, (_Float16)v.y, (_Float16)v.z, (_Float16)v.w };
    ((half4*)dst)[i] = o;
  }
}

// ---------------- GEMM: C = A * B^T, A[M][1024] f16, B[N][1024] f16 ----------------
// 128x128 tile, 4 waves (2x2), BK=32, 16x16x32 f16 MFMA (m97 structure).
// MODE 0: QKV projection epilogue -> Q(scaled)[bh][s][64], K[bh][s][64], Vt[bh][64][s]  (f16)
// MODE 1: plain f32 store to out[M][1024]
template<int MODE>
__global__ __launch_bounds__(256)
void gemm_hk(const _Float16* __restrict__ A, const _Float16* __restrict__ B,
             _Float16* __restrict__ oQ, _Float16* __restrict__ oK,
             _Float16* __restrict__ oVt, float* __restrict__ oF) {
  __shared__ _Float16 As[128*32];
  __shared__ _Float16 Bs[128*32];
  const int tid  = threadIdx.x;
  const int wid  = tid >> 6, lane = tid & 63;
  const int wm   = wid >> 1, wn = wid & 1;
  const int fr   = lane & 15, fg = lane >> 4;
  const long m0  = (long)blockIdx.x * 128;
  const long n0  = (long)blockIdx.y * 128;
  const int lrow = lane >> 2;            // 16 rows per instr (4 lanes/row)
  const int lcol = (lane & 3) * 8;       // halfs
  const _Float16* ga0 = A + (m0 + wid*32 + lrow) * 1024 + lcol;
  const _Float16* gb0 = B + (n0 + wid*32 + lrow) * 1024 + lcol;
  _Float16* lA = &As[wid*32*32];
  _Float16* lB = &Bs[wid*32*32];

  f32x4 acc[4][4] = {};

  for (int k0 = 0; k0 < 1024; k0 += 32) {
    gload16(ga0 + k0,             lA);
    gload16(ga0 + k0 + 16*1024,   lA + 16*32);
    gload16(gb0 + k0,             lB);
    gload16(gb0 + k0 + 16*1024,   lB + 16*32);
    __syncthreads();
    half8 af[4], bf[4];
#pragma unroll
    for (int i = 0; i < 4; ++i) {
      af[i] = *(const half8*)&As[(wm*64 + i*16 + fr)*32 + fg*8];
      bf[i] = *(const half8*)&Bs[(wn*64 + i*16 + fr)*32 + fg*8];
    }
#pragma unroll
    for (int i = 0; i < 4; ++i)
#pragma unroll
      for (int j = 0; j < 4; ++j)
        acc[i][j] = __builtin_amdgcn_mfma_f32_16x16x32_f16(af[i], bf[j], acc[i][j], 0, 0, 0);
    __syncthreads();
  }

  if (MODE == 0) {
    const int which = (int)(n0 >> 10);               // 0=Q 1=K 2=V (tiles never straddle)
    const int nloc0 = ((int)n0 & 1023) + wn*64;
#pragma unroll
    for (int i = 0; i < 4; ++i) {
      const long r0 = m0 + wm*64 + i*16 + fg*4;
      const int  bb = (int)(r0 >> 11);
      const int  s  = (int)(r0 & 2047);
#pragma unroll
      for (int j = 0; j < 4; ++j) {
        const int nl = nloc0 + j*16 + fr;
        const int h  = nl >> 6, d = nl & 63;
        const long bh = (long)(bb*NH + h);
        if (which == 0) {
#pragma unroll
          for (int r = 0; r < 4; ++r)
            oQ[(bh*SEQ + s + r)*HD + d] = (_Float16)(acc[i][j][r] * 0.125f);
        } else if (which == 1) {
#pragma unroll
          for (int r = 0; r < 4; ++r)
            oK[(bh*SEQ + s + r)*HD + d] = (_Float16)acc[i][j][r];
        } else {
          half4 pk = { (_Float16)acc[i][j][0], (_Float16)acc[i][j][1],
                       (_Float16)acc[i][j][2], (_Float16)acc[i][j][3] };
          *(half4*)&oVt[(bh*HD + d)*SEQ + s] = pk;   // s % 4 == 0, 8B aligned
        }
      }
    }
  } else {
#pragma unroll
    for (int i = 0; i < 4; ++i) {
      const long r0 = m0 + wm*64 + i*16 + fg*4;
#pragma unroll
      for (int j = 0; j < 4; ++j) {
        const long col = n0 + wn*64 + j*16 + fr;
#pragma unroll
        for (int r = 0; r < 4; ++r)
          oF[(r0 + r)*DM + col] = acc[i][j][r];
      }
    }
  }
}

// ---------------- RoPE in place on Q and K [bh][s][64] ----------------
__global__ void rope_k(_Float16* __restrict__ Q, _Float16* __restrict__ K,
                       const int* __restrict__ tp) {
  const int t = blockIdx.x * blockDim.x + threadIdx.x;   // over SEQ*32
  const int s = t >> 5, p = t & 31;
  _Float16* base = blockIdx.z ? K : Q;
  half2v* ptr = (half2v*)(base + ((long)blockIdx.y * SEQ + s) * HD) + p;
  half2v v = *ptr;
  const float pos = (float)tp[s];
  // inv_freq = 10000^(-p/32) = exp2(-p * log2(10000)/32)
  const float inv = exp2f(-0.41524101186f * (float)p);
  const float f = pos * inv;
  float sn, cs;
  __sincosf(f, &sn, &cs);
  const float xe = (float)v[0], xo = (float)v[1];
  half2v o = { (_Float16)(xe*cs - xo*sn), (_Float16)(xo*cs + xe*sn) };
  *ptr = o;
}

// ---------------- causal flash attention ----------------
// grid (S/64, BH). 4 waves x 16 q-rows. KV tiles of 64.
// K[bh][s][64], Vt[bh][64][s] staged to LDS with XOR slot-swizzle (src-side pre-swizzle,
// read-side same XOR) to break the 128B-row bank conflict. Q pre-scaled by 1/8.
__global__ __launch_bounds__(256)
void fattn(const _Float16* __restrict__ Q, const _Float16* __restrict__ K,
           const _Float16* __restrict__ Vt, _Float16* __restrict__ O) {
  __shared__ _Float16 Ks[64*64];
  __shared__ _Float16 Vs[64*64];
  __shared__ _Float16 Ps[4][16*72];      // padded stride 72 -> conflict-free
  const int tid = threadIdx.x, wid = tid >> 6, lane = tid & 63;
  const int fr = lane & 15, fg = lane >> 4;
  const int bh = blockIdx.y;
  const int b = bh >> 4, h = bh & 15;
  const int q0 = blockIdx.x * 64;
  const int qw = q0 + wid * 16;
  const _Float16* Qb = Q + (long)bh * SEQ * HD;
  const _Float16* Kb = K + (long)bh * SEQ * HD;
  const _Float16* Vb = Vt + (long)bh * HD * SEQ;

  const half8 qf0 = *(const half8*)&Qb[(qw + fr)*HD + fg*8];
  const half8 qf1 = *(const half8*)&Qb[(qw + fr)*HD + 32 + fg*8];

  f32x4 oacc[4] = {};
  float m_r[4], l_r[4];
#pragma unroll
  for (int r = 0; r < 4; ++r) { m_r[r] = -1e30f; l_r[r] = 0.f; }

  const int srow = lane >> 3;                 // 0..7 (row within 8-row chunk)
  const int sc16 = (lane & 7) ^ srow;         // pre-swizzled source slot

  for (int kv0 = 0; kv0 <= q0; kv0 += 64) {
    const int r1 = wid*16 + srow, r2 = r1 + 8;    // r&7 == srow for both
    gload16(Kb + (long)(kv0 + r1)*HD + sc16*8, &Ks[(wid*16)*64]);
    gload16(Kb + (long)(kv0 + r2)*HD + sc16*8, &Ks[(wid*16 + 8)*64]);
    gload16(Vb + (long)r1*SEQ + kv0 + sc16*8,  &Vs[(wid*16)*64]);
    gload16(Vb + (long)r2*SEQ + kv0 + sc16*8,  &Vs[(wid*16 + 8)*64]);
    __syncthreads();

    // S = Q K^T  (rows=q within wave, cols=kv)
    f32x4 sacc[4];
#pragma unroll
    for (int n = 0; n < 4; ++n) {
      const int row = n*16 + fr;
      const int sw = (row & 7) << 4;
      const half8 k0v = *(const half8*)((const char*)Ks + row*128 + ((fg*16) ^ sw));
      const half8 k1v = *(const half8*)((const char*)Ks + row*128 + ((64 + fg*16) ^ sw));
      f32x4 z = {0.f, 0.f, 0.f, 0.f};
      z = __builtin_amdgcn_mfma_f32_16x16x32_f16(qf0, k0v, z, 0, 0, 0);
      sacc[n] = __builtin_amdgcn_mfma_f32_16x16x32_f16(qf1, k1v, z, 0, 0, 0);
    }

    if (kv0 + 63 > qw) {      // diagonal / masked region for this wave
#pragma unroll
      for (int n = 0; n < 4; ++n) {
        const int kv = kv0 + n*16 + fr;
#pragma unroll
        for (int r = 0; r < 4; ++r)
          if (kv > qw + fg*4 + r) sacc[n][r] = -1e30f;
      }
    }

    // online softmax (per q-row; row stats live replicated across the 16-lane group)
    float pm[4];
#pragma unroll
    for (int r = 0; r < 4; ++r)
      pm[r] = fmaxf(fmaxf(sacc[0][r], sacc[1][r]), fmaxf(sacc[2][r], sacc[3][r]));
#pragma unroll
    for (int off = 1; off < 16; off <<= 1)
#pragma unroll
      for (int r = 0; r < 4; ++r)
        pm[r] = fmaxf(pm[r], __shfl_xor(pm[r], off));
    float fac[4], ps[4];
#pragma unroll
    for (int r = 0; r < 4; ++r) {
      const float mn = fmaxf(m_r[r], pm[r]);
      fac[r] = __expf(m_r[r] - mn);
      m_r[r] = mn;
      ps[r] = 0.f;
    }
#pragma unroll
    for (int n = 0; n < 4; ++n)
#pragma unroll
      for (int r = 0; r < 4; ++r) {
        const float p = __expf(sacc[n][r] - m_r[r]);
        sacc[n][r] = p;
        ps[r] += p;
      }
#pragma unroll
    for (int off = 1; off < 16; off <<= 1)
#pragma unroll
      for (int r = 0; r < 4; ++r)
        ps[r] += __shfl_xor(ps[r], off);
#pragma unroll
    for (int r = 0; r < 4; ++r)
      l_r[r] = l_r[r]*fac[r] + ps[r];
#pragma unroll
    for (int n = 0; n < 4; ++n)
#pragma unroll
      for (int r = 0; r < 4; ++r)
        oacc[n][r] *= fac[r];

    // P -> LDS (per-wave region), then P*V
    _Float16* Pw = &Ps[wid][0];
#pragma unroll
    for (int n = 0; n < 4; ++n)
#pragma unroll
      for (int r = 0; r < 4; ++r)
        Pw[(fg*4 + r)*72 + n*16 + fr] = (_Float16)sacc[n][r];
    __syncthreads();

#pragma unroll
    for (int ks = 0; ks < 2; ++ks) {
      const half8 pf = *(const half8*)&Pw[fr*72 + ks*32 + fg*8];
#pragma unroll
      for (int n = 0; n < 4; ++n) {
        const int row = n*16 + fr;
        const int sw = (row & 7) << 4;
        const half8 vf = *(const half8*)((const char*)Vs + row*128 + (((ks*32 + fg*8)*2) ^ sw));
        oacc[n] = __builtin_amdgcn_mfma_f32_16x16x32_f16(pf, vf, oacc[n], 0, 0, 0);
      }
    }
    __syncthreads();
  }

  // epilogue: attn[b][s][h*64+d] f16
#pragma unroll
  for (int n = 0; n < 4; ++n)
#pragma unroll
    for (int r = 0; r < 4; ++r) {
      const long s = qw + fg*4 + r;
      O[((long)b*SEQ + s)*DM + h*64 + n*16 + fr] = (_Float16)(oacc[n][r] / l_r[r]);
    }
}

extern "C" void kernel_launch(void* const* d_in, const int* in_sizes, int n_in,
                              void* d_out, int out_size, void* d_ws, size_t ws_size,
                              hipStream_t stream) {
  const float* x  = (const float*)d_in[0];
  const float* Wq = (const float*)d_in[1];
  const float* Wk = (const float*)d_in[2];
  const float* Wv = (const float*)d_in[3];
  const float* Wo = (const float*)d_in[4];
  const int*   tp = (const int*)d_in[5];
  float* out = (float*)d_out;

  char* ws = (char*)d_ws;
  _Float16* xh   = (_Float16*)(ws);                  // 16 MB  [8192][1024]
  _Float16* Wqkv = (_Float16*)(ws + (16u << 20));    //  6 MB  [3072][1024]
  _Float16* Woh  = (_Float16*)(ws + (22u << 20));    //  2 MB  [1024][1024]
  _Float16* Qb   = (_Float16*)(ws + (24u << 20));    // 16 MB  [64][2048][64]
  _Float16* Kb   = (_Float16*)(ws + (40u << 20));    // 16 MB
  _Float16* Vtb  = (_Float16*)(ws + (56u << 20));    // 16 MB  [64][64][2048]
  _Float16* attn = (_Float16*)(ws + (72u << 20));    // 16 MB  [8192][1024]

  cvt4<<<8192, 256, 0, stream>>>(x,  xh, 2097152);
  cvt4<<<1024, 256, 0, stream>>>(Wq, Wqkv,               262144);
  cvt4<<<1024, 256, 0, stream>>>(Wk, Wqkv + (1u << 20),  262144);
  cvt4<<<1024, 256, 0, stream>>>(Wv, Wqkv + (2u << 20),  262144);
  cvt4<<<1024, 256, 0, stream>>>(Wo, Woh,                262144);

  gemm_hk<0><<<dim3(64, 24), 256, 0, stream>>>(xh, Wqkv, Qb, Kb, Vtb, nullptr);
  rope_k<<<dim3(256, 64, 2), 256, 0, stream>>>(Qb, Kb, tp);
  fattn<<<dim3(32, 64), 256, 0, stream>>>(Qb, Kb, Vtb, attn);
  gemm_hk<1><<<dim3(64, 8), 256, 0, stream>>>(attn, Woh, nullptr, nullptr, nullptr, out);
}

// Round 2
// 236.800 us; speedup vs baseline: 1.3723x; 1.3723x over previous
//
#include <hip/hip_runtime.h>
#include <hip/hip_fp16.h>

typedef _Float16 half8 __attribute__((ext_vector_type(8)));
typedef _Float16 half4 __attribute__((ext_vector_type(4)));
typedef _Float16 half2v __attribute__((ext_vector_type(2)));
typedef float f32x4 __attribute__((ext_vector_type(4)));

#define SEQ   2048
#define DM    1024
#define NH    16
#define HD    64
#define BSZ   4
#define BH_N  (BSZ*NH)

// async global->LDS, 16B per lane. LDS dest = wave-uniform base + lane*16.
__device__ __forceinline__ void gload16(const void* g, void* l) {
  __builtin_amdgcn_global_load_lds((const __attribute__((address_space(1))) void*)g,
                                   (__attribute__((address_space(3))) void*)l,
                                   16, 0, 0);
}

// ---------------- fp32 -> fp16 convert (vectorized) ----------------
__global__ void cvt4(const float* __restrict__ src, _Float16* __restrict__ dst, int n4) {
  int i = blockIdx.x * blockDim.x + threadIdx.x;
  if (i < n4) {
    float4 v = ((const float4*)src)[i];
    half4 o = { (_Float16)v.x, (_Float16)v.y, (_Float16)v.z, (_Float16)v.w };
    ((half4*)dst)[i] = o;
  }
}

// ---------------- GEMM: C = A * B^T, A[M][1024] f16, B[N][1024] f16 ----------------
// 128x128 tile, 4 waves (2x2), BK=32, 16x16x32 f16 MFMA (m97 structure).
// MODE 0: QKV projection epilogue -> Q(scaled)[bh][s][64], K[bh][s][64], Vt[bh][64][s]  (f16)
// MODE 1: plain f32 store to out[M][1024]
template<int MODE>
__global__ __launch_bounds__(256)
void gemm_hk(const _Float16* __restrict__ A, const _Float16* __restrict__ B,
             _Float16* __restrict__ oQ, _Float16* __restrict__ oK,
             _Float16* __restrict__ oVt, float* __restrict__ oF) {
  __shared__ _Float16 As[128*32];
  __shared__ _Float16 Bs[128*32];
  const int tid  = threadIdx.x;
  const int wid  = tid >> 6, lane = tid & 63;
  const int wm   = wid >> 1, wn = wid & 1;
  const int fr   = lane & 15, fg = lane >> 4;
  const long m0  = (long)blockIdx.x * 128;
  const long n0  = (long)blockIdx.y * 128;
  const int lrow = lane >> 2;            // 16 rows per instr (4 lanes/row)
  const int lcol = (lane & 3) * 8;       // halfs
  const _Float16* ga0 = A + (m0 + wid*32 + lrow) * 1024 + lcol;
  const _Float16* gb0 = B + (n0 + wid*32 + lrow) * 1024 + lcol;
  _Float16* lA = &As[wid*32*32];
  _Float16* lB = &Bs[wid*32*32];

  f32x4 acc[4][4] = {};

  for (int k0 = 0; k0 < 1024; k0 += 32) {
    gload16(ga0 + k0,             lA);
    gload16(ga0 + k0 + 16*1024,   lA + 16*32);
    gload16(gb0 + k0,             lB);
    gload16(gb0 + k0 + 16*1024,   lB + 16*32);
    __syncthreads();
    half8 af[4], bf[4];
#pragma unroll
    for (int i = 0; i < 4; ++i) {
      af[i] = *(const half8*)&As[(wm*64 + i*16 + fr)*32 + fg*8];
      bf[i] = *(const half8*)&Bs[(wn*64 + i*16 + fr)*32 + fg*8];
    }
#pragma unroll
    for (int i = 0; i < 4; ++i)
#pragma unroll
      for (int j = 0; j < 4; ++j)
        acc[i][j] = __builtin_amdgcn_mfma_f32_16x16x32_f16(af[i], bf[j], acc[i][j], 0, 0, 0);
    __syncthreads();
  }

  if (MODE == 0) {
    const int which = (int)(n0 >> 10);               // 0=Q 1=K 2=V (tiles never straddle)
    const int nloc0 = ((int)n0 & 1023) + wn*64;
#pragma unroll
    for (int i = 0; i < 4; ++i) {
      const long r0 = m0 + wm*64 + i*16 + fg*4;
      const int  bb = (int)(r0 >> 11);
      const int  s  = (int)(r0 & 2047);
#pragma unroll
      for (int j = 0; j < 4; ++j) {
        const int nl = nloc0 + j*16 + fr;
        const int h  = nl >> 6, d = nl & 63;
        const long bh = (long)(bb*NH + h);
        if (which == 0) {
#pragma unroll
          for (int r = 0; r < 4; ++r)
            oQ[(bh*SEQ + s + r)*HD + d] = (_Float16)(acc[i][j][r] * 0.125f);
        } else if (which == 1) {
#pragma unroll
          for (int r = 0; r < 4; ++r)
            oK[(bh*SEQ + s + r)*HD + d] = (_Float16)acc[i][j][r];
        } else {
          half4 pk = { (_Float16)acc[i][j][0], (_Float16)acc[i][j][1],
                       (_Float16)acc[i][j][2], (_Float16)acc[i][j][3] };
          *(half4*)&oVt[(bh*HD + d)*SEQ + s] = pk;   // s % 4 == 0, 8B aligned
        }
      }
    }
  } else {
#pragma unroll
    for (int i = 0; i < 4; ++i) {
      const long r0 = m0 + wm*64 + i*16 + fg*4;
#pragma unroll
      for (int j = 0; j < 4; ++j) {
        const long col = n0 + wn*64 + j*16 + fr;
#pragma unroll
        for (int r = 0; r < 4; ++r)
          oF[(r0 + r)*DM + col] = acc[i][j][r];
      }
    }
  }
}

// ---------------- RoPE in place on Q and K [bh][s][64] ----------------
__global__ void rope_k(_Float16* __restrict__ Q, _Float16* __restrict__ K,
                       const int* __restrict__ tp) {
  const int t = blockIdx.x * blockDim.x + threadIdx.x;   // over SEQ*32
  const int s = t >> 5, p = t & 31;
  _Float16* base = blockIdx.z ? K : Q;
  half2v* ptr = (half2v*)(base + ((long)blockIdx.y * SEQ + s) * HD) + p;
  half2v v = *ptr;
  const float pos = (float)tp[s];
  // inv_freq = 10000^(-p/32) = exp2(-p * log2(10000)/32)
  const float inv = exp2f(-0.41524101186f * (float)p);
  const float f = pos * inv;
  float sn, cs;
  __sincosf(f, &sn, &cs);
  const float xe = (float)v[0], xo = (float)v[1];
  half2v o = { (_Float16)(xe*cs - xo*sn), (_Float16)(xo*cs + xe*sn) };
  *ptr = o;
}

// ---------------- causal flash attention ----------------
// grid (BH=64, 32 qtiles). 4 waves x 16 q-rows. KV tiles of 64.
// Heavy-first: q0 = (31 - blockIdx.y)*64 so 32-tile blocks dispatch first.
// Double-buffered KV (2-phase pipeline, ONE barrier per tile): stage t+1 into
// buf^1 before computing t; the end-of-tile __syncthreads (implicit vmcnt(0))
// drains prefetch loads AFTER compute -> HBM latency hidden.
// K[bh][s][64], Vt[bh][64][s] staged with XOR slot-swizzle (src-side pre-swizzle,
// read-side same XOR). Q pre-scaled by 1/8. P lives in per-wave LDS (no barrier).
__global__ __launch_bounds__(256)
void fattn(const _Float16* __restrict__ Q, const _Float16* __restrict__ K,
           const _Float16* __restrict__ Vt, _Float16* __restrict__ O) {
  __shared__ _Float16 Ks[2][64*64];
  __shared__ _Float16 Vs[2][64*64];
  __shared__ _Float16 Ps[4][16*72];      // per-wave region, stride 72 -> conflict-free
  const int tid = threadIdx.x, wid = tid >> 6, lane = tid & 63;
  const int fr = lane & 15, fg = lane >> 4;
  const int bh = blockIdx.x;
  const int b = bh >> 4, h = bh & 15;
  const int q0 = (int)(gridDim.y - 1 - blockIdx.y) * 64;
  const int qw = q0 + wid * 16;
  const _Float16* Qb = Q + (long)bh * SEQ * HD;
  const _Float16* Kb = K + (long)bh * SEQ * HD;
  const _Float16* Vb = Vt + (long)bh * HD * SEQ;

  const half8 qf0 = *(const half8*)&Qb[(qw + fr)*HD + fg*8];
  const half8 qf1 = *(const half8*)&Qb[(qw + fr)*HD + 32 + fg*8];

  f32x4 oacc[4] = {};
  float m_r[4], l_r[4];
#pragma unroll
  for (int r = 0; r < 4; ++r) { m_r[r] = -1e30f; l_r[r] = 0.f; }

  const int srow = lane >> 3;                 // 0..7 (row within 8-row chunk)
  const int sc16 = (lane & 7) ^ srow;         // pre-swizzled source slot
  const int r1 = wid*16 + srow, r2 = r1 + 8;  // rows this wave stages

  _Float16* Pw = &Ps[wid][0];
  const int nt = q0/64 + 1;

  // prologue: stage tile 0 into buf 0; barrier drains it (latency exposed once)
  {
    gload16(Kb + (long)r1*HD + sc16*8, &Ks[0][(wid*16)*64]);
    gload16(Kb + (long)r2*HD + sc16*8, &Ks[0][(wid*16 + 8)*64]);
    gload16(Vb + (long)r1*SEQ + sc16*8, &Vs[0][(wid*16)*64]);
    gload16(Vb + (long)r2*SEQ + sc16*8, &Vs[0][(wid*16 + 8)*64]);
  }
  __syncthreads();

  int cur = 0;
  for (int t = 0; t < nt; ++t) {
    const int kv0 = t * 64;

    // prefetch next tile into the other buffer (drained by end-of-tile barrier)
    if (t + 1 < nt) {
      const int nkv = kv0 + 64;
      gload16(Kb + (long)(nkv + r1)*HD + sc16*8, &Ks[cur^1][(wid*16)*64]);
      gload16(Kb + (long)(nkv + r2)*HD + sc16*8, &Ks[cur^1][(wid*16 + 8)*64]);
      gload16(Vb + (long)r1*SEQ + nkv + sc16*8,  &Vs[cur^1][(wid*16)*64]);
      gload16(Vb + (long)r2*SEQ + nkv + sc16*8,  &Vs[cur^1][(wid*16 + 8)*64]);
    }

    const _Float16* Kc = &Ks[cur][0];
    const _Float16* Vc = &Vs[cur][0];

    // S = Q K^T  (rows=q within wave, cols=kv)
    f32x4 sacc[4];
    __builtin_amdgcn_s_setprio(1);
#pragma unroll
    for (int n = 0; n < 4; ++n) {
      const int row = n*16 + fr;
      const int sw = (row & 7) << 4;
      const half8 k0v = *(const half8*)((const char*)Kc + row*128 + ((fg*16) ^ sw));
      const half8 k1v = *(const half8*)((const char*)Kc + row*128 + ((64 + fg*16) ^ sw));
      f32x4 z = {0.f, 0.f, 0.f, 0.f};
      z = __builtin_amdgcn_mfma_f32_16x16x32_f16(qf0, k0v, z, 0, 0, 0);
      sacc[n] = __builtin_amdgcn_mfma_f32_16x16x32_f16(qf1, k1v, z, 0, 0, 0);
    }
    __builtin_amdgcn_s_setprio(0);

    if (kv0 + 63 > qw) {      // diagonal / masked region for this wave
#pragma unroll
      for (int n = 0; n < 4; ++n) {
        const int kv = kv0 + n*16 + fr;
#pragma unroll
        for (int r = 0; r < 4; ++r)
          if (kv > qw + fg*4 + r) sacc[n][r] = -1e30f;
      }
    }

    // online softmax (per q-row; row stats replicated across the 16-lane group)
    float pm[4];
#pragma unroll
    for (int r = 0; r < 4; ++r)
      pm[r] = fmaxf(fmaxf(sacc[0][r], sacc[1][r]), fmaxf(sacc[2][r], sacc[3][r]));
#pragma unroll
    for (int off = 1; off < 16; off <<= 1)
#pragma unroll
      for (int r = 0; r < 4; ++r)
        pm[r] = fmaxf(pm[r], __shfl_xor(pm[r], off));
    float fac[4], ps[4];
#pragma unroll
    for (int r = 0; r < 4; ++r) {
      const float mn = fmaxf(m_r[r], pm[r]);
      fac[r] = __expf(m_r[r] - mn);
      m_r[r] = mn;
      ps[r] = 0.f;
    }
#pragma unroll
    for (int n = 0; n < 4; ++n)
#pragma unroll
      for (int r = 0; r < 4; ++r) {
        const float p = __expf(sacc[n][r] - m_r[r]);
        sacc[n][r] = p;
        ps[r] += p;
      }
#pragma unroll
    for (int off = 1; off < 16; off <<= 1)
#pragma unroll
      for (int r = 0; r < 4; ++r)
        ps[r] += __shfl_xor(ps[r], off);
#pragma unroll
    for (int r = 0; r < 4; ++r)
      l_r[r] = l_r[r]*fac[r] + ps[r];
#pragma unroll
    for (int n = 0; n < 4; ++n)
#pragma unroll
      for (int r = 0; r < 4; ++r)
        oacc[n][r] *= fac[r];

    // P -> per-wave LDS (no cross-wave barrier needed), then P*V
#pragma unroll
    for (int n = 0; n < 4; ++n)
#pragma unroll
      for (int r = 0; r < 4; ++r)
        Pw[(fg*4 + r)*72 + n*16 + fr] = (_Float16)sacc[n][r];

    __builtin_amdgcn_s_setprio(1);
#pragma unroll
    for (int ks = 0; ks < 2; ++ks) {
      const half8 pf = *(const half8*)&Pw[fr*72 + ks*32 + fg*8];
#pragma unroll
      for (int n = 0; n < 4; ++n) {
        const int row = n*16 + fr;
        const int sw = (row & 7) << 4;
        const half8 vf = *(const half8*)((const char*)Vc + row*128 + (((ks*32 + fg*8)*2) ^ sw));
        oacc[n] = __builtin_amdgcn_mfma_f32_16x16x32_f16(pf, vf, oacc[n], 0, 0, 0);
      }
    }
    __builtin_amdgcn_s_setprio(0);

    __syncthreads();           // implicit vmcnt(0): prefetch drained; buffers swappable
    cur ^= 1;
  }

  // epilogue: attn[b][s][h*64+d] f16
  float rl[4];
#pragma unroll
  for (int r = 0; r < 4; ++r) rl[r] = __builtin_amdgcn_rcpf(l_r[r]);
#pragma unroll
  for (int n = 0; n < 4; ++n)
#pragma unroll
    for (int r = 0; r < 4; ++r) {
      const long s = qw + fg*4 + r;
      O[((long)b*SEQ + s)*DM + h*64 + n*16 + fr] = (_Float16)(oacc[n][r] * rl[r]);
    }
}

extern "C" void kernel_launch(void* const* d_in, const int* in_sizes, int n_in,
                              void* d_out, int out_size, void* d_ws, size_t ws_size,
                              hipStream_t stream) {
  const float* x  = (const float*)d_in[0];
  const float* Wq = (const float*)d_in[1];
  const float* Wk = (const float*)d_in[2];
  const float* Wv = (const float*)d_in[3];
  const float* Wo = (const float*)d_in[4];
  const int*   tp = (const int*)d_in[5];
  float* out = (float*)d_out;

  char* ws = (char*)d_ws;
  _Float16* xh   = (_Float16*)(ws);                  // 16 MB  [8192][1024]
  _Float16* Wqkv = (_Float16*)(ws + (16u << 20));    //  6 MB  [3072][1024]
  _Float16* Woh  = (_Float16*)(ws + (22u << 20));    //  2 MB  [1024][1024]
  _Float16* Qb   = (_Float16*)(ws + (24u << 20));    // 16 MB  [64][2048][64]
  _Float16* Kb   = (_Float16*)(ws + (40u << 20));    // 16 MB
  _Float16* Vtb  = (_Float16*)(ws + (56u << 20));    // 16 MB  [64][64][2048]
  _Float16* attn = (_Float16*)(ws + (72u << 20));    // 16 MB  [8192][1024]

  cvt4<<<8192, 256, 0, stream>>>(x,  xh, 2097152);
  cvt4<<<1024, 256, 0, stream>>>(Wq, Wqkv,               262144);
  cvt4<<<1024, 256, 0, stream>>>(Wk, Wqkv + (1u << 20),  262144);
  cvt4<<<1024, 256, 0, stream>>>(Wv, Wqkv + (2u << 20),  262144);
  cvt4<<<1024, 256, 0, stream>>>(Wo, Woh,                262144);

  gemm_hk<0><<<dim3(64, 24), 256, 0, stream>>>(xh, Wqkv, Qb, Kb, Vtb, nullptr);
  rope_k<<<dim3(256, 64, 2), 256, 0, stream>>>(Qb, Kb, tp);
  fattn<<<dim3(64, 32), 256, 0, stream>>>(Qb, Kb, Vtb, attn);
  gemm_hk<1><<<dim3(64, 8), 256, 0, stream>>>(attn, Woh, nullptr, nullptr, nullptr, out);
}

// Round 3
// 200.185 us; speedup vs baseline: 1.6233x; 1.1829x over previous
//
#include <hip/hip_runtime.h>
#include <hip/hip_fp16.h>

typedef _Float16 half8 __attribute__((ext_vector_type(8)));
typedef _Float16 half4 __attribute__((ext_vector_type(4)));
typedef _Float16 half2v __attribute__((ext_vector_type(2)));
typedef float f32x4 __attribute__((ext_vector_type(4)));

#define SEQ   2048
#define DM    1024
#define NH    16
#define HD    64
#define BSZ   4

// async global->LDS, 16B per lane. LDS dest = wave-uniform base + lane*16.
__device__ __forceinline__ void gload16(const void* g, void* l) {
  __builtin_amdgcn_global_load_lds((const __attribute__((address_space(1))) void*)g,
                                   (__attribute__((address_space(3))) void*)l,
                                   16, 0, 0);
}

// ---------------- fp32 -> fp16 convert (vectorized) ----------------
__global__ void cvt4(const float* __restrict__ src, _Float16* __restrict__ dst, int n4) {
  int i = blockIdx.x * blockDim.x + threadIdx.x;
  if (i < n4) {
    float4 v = ((const float4*)src)[i];
    half4 o = { (_Float16)v.x, (_Float16)v.y, (_Float16)v.z, (_Float16)v.w };
    ((half4*)dst)[i] = o;
  }
}

// ---------------- GEMM: C = A * B^T, A[M][1024] f16, B[N][1024] f16 ----------------
// 128x128 tile, 4 waves (2x2), BK=32, 16x16x32 f16 MFMA (m97 structure).
// MODE 0: QKV projection epilogue -> Q(scaled)[bh][s][64], K[bh][s][64], Vt[bh][64][s]  (f16)
// MODE 1: plain f32 store to out[M][1024]
template<int MODE>
__global__ __launch_bounds__(256)
void gemm_hk(const _Float16* __restrict__ A, const _Float16* __restrict__ B,
             _Float16* __restrict__ oQ, _Float16* __restrict__ oK,
             _Float16* __restrict__ oVt, float* __restrict__ oF) {
  __shared__ _Float16 As[128*32];
  __shared__ _Float16 Bs[128*32];
  const int tid  = threadIdx.x;
  const int wid  = tid >> 6, lane = tid & 63;
  const int wm   = wid >> 1, wn = wid & 1;
  const int fr   = lane & 15, fg = lane >> 4;
  const long m0  = (long)blockIdx.x * 128;
  const long n0  = (long)blockIdx.y * 128;
  const int lrow = lane >> 2;            // 16 rows per instr (4 lanes/row)
  const int lcol = (lane & 3) * 8;       // halfs
  const _Float16* ga0 = A + (m0 + wid*32 + lrow) * 1024 + lcol;
  const _Float16* gb0 = B + (n0 + wid*32 + lrow) * 1024 + lcol;
  _Float16* lA = &As[wid*32*32];
  _Float16* lB = &Bs[wid*32*32];

  f32x4 acc[4][4] = {};

  for (int k0 = 0; k0 < 1024; k0 += 32) {
    gload16(ga0 + k0,             lA);
    gload16(ga0 + k0 + 16*1024,   lA + 16*32);
    gload16(gb0 + k0,             lB);
    gload16(gb0 + k0 + 16*1024,   lB + 16*32);
    __syncthreads();
    half8 af[4], bf[4];
#pragma unroll
    for (int i = 0; i < 4; ++i) {
      af[i] = *(const half8*)&As[(wm*64 + i*16 + fr)*32 + fg*8];
      bf[i] = *(const half8*)&Bs[(wn*64 + i*16 + fr)*32 + fg*8];
    }
#pragma unroll
    for (int i = 0; i < 4; ++i)
#pragma unroll
      for (int j = 0; j < 4; ++j)
        acc[i][j] = __builtin_amdgcn_mfma_f32_16x16x32_f16(af[i], bf[j], acc[i][j], 0, 0, 0);
    __syncthreads();
  }

  if (MODE == 0) {
    const int which = (int)(n0 >> 10);               // 0=Q 1=K 2=V (tiles never straddle)
    const int nloc0 = ((int)n0 & 1023) + wn*64;
#pragma unroll
    for (int i = 0; i < 4; ++i) {
      const long r0 = m0 + wm*64 + i*16 + fg*4;
      const int  bb = (int)(r0 >> 11);
      const int  s  = (int)(r0 & 2047);
#pragma unroll
      for (int j = 0; j < 4; ++j) {
        const int nl = nloc0 + j*16 + fr;
        const int h  = nl >> 6, d = nl & 63;
        const long bh = (long)(bb*NH + h);
        if (which == 0) {
#pragma unroll
          for (int r = 0; r < 4; ++r)
            oQ[(bh*SEQ + s + r)*HD + d] = (_Float16)(acc[i][j][r] * 0.125f);
        } else if (which == 1) {
#pragma unroll
          for (int r = 0; r < 4; ++r)
            oK[(bh*SEQ + s + r)*HD + d] = (_Float16)acc[i][j][r];
        } else {
          half4 pk = { (_Float16)acc[i][j][0], (_Float16)acc[i][j][1],
                       (_Float16)acc[i][j][2], (_Float16)acc[i][j][3] };
          *(half4*)&oVt[(bh*HD + d)*SEQ + s] = pk;   // s % 4 == 0, 8B aligned
        }
      }
    }
  } else {
#pragma unroll
    for (int i = 0; i < 4; ++i) {
      const long r0 = m0 + wm*64 + i*16 + fg*4;
#pragma unroll
      for (int j = 0; j < 4; ++j) {
        const long col = n0 + wn*64 + j*16 + fr;
#pragma unroll
        for (int r = 0; r < 4; ++r)
          oF[(r0 + r)*DM + col] = acc[i][j][r];
      }
    }
  }
}

// ---------------- RoPE in place on Q and K [bh][s][64] ----------------
__global__ void rope_k(_Float16* __restrict__ Q, _Float16* __restrict__ K,
                       const int* __restrict__ tp) {
  const int t = blockIdx.x * blockDim.x + threadIdx.x;   // over SEQ*32
  const int s = t >> 5, p = t & 31;
  _Float16* base = blockIdx.z ? K : Q;
  half2v* ptr = (half2v*)(base + ((long)blockIdx.y * SEQ + s) * HD) + p;
  half2v v = *ptr;
  const float pos = (float)tp[s];
  const float inv = exp2f(-0.41524101186f * (float)p);
  const float f = pos * inv;
  float sn, cs;
  __sincosf(f, &sn, &cs);
  const float xe = (float)v[0], xo = (float)v[1];
  half2v o = { (_Float16)(xe*cs - xo*sn), (_Float16)(xo*cs + xe*sn) };
  *ptr = o;
}

// ---------------- causal flash attention (swapped-operand form) ----------------
// grid (BH=64, 16 qtiles of 128). 4 waves x 32 q-rows (2 sets of 16). KV tiles of 64.
// All MFMAs swapped: S^T = mfma(K,Q) so lane fr = q-col -> row stats are LANE-LOCAL
// scalars (2 shuffles per reduce); O^T = mfma(V,P) so rescale needs no broadcast.
// P stored packed (half4 ds_write_b64) into XOR-swizzled stride-64 LDS.
// K[bh][s][64], Vt[bh][64][s] staged via global_load_lds with src-side pre-swizzle.
// LDS = 40960 B exactly -> 4 blocks/CU. Q pre-scaled by 1/8.
__global__ __launch_bounds__(256, 4)
void fattn(const _Float16* __restrict__ Q, const _Float16* __restrict__ K,
           const _Float16* __restrict__ Vt, _Float16* __restrict__ O) {
  __shared__ _Float16 Ks[2][64*64];
  __shared__ _Float16 Vs[2][64*64];
  __shared__ _Float16 Ps[4][16*64];      // per-wave, XOR-swizzled, stride 64
  const int tid = threadIdx.x, wid = tid >> 6, lane = tid & 63;
  const int fr = lane & 15, fg = lane >> 4;
  const int bh = blockIdx.x;
  const int b = bh >> 4, h = bh & 15;
  // balanced heavy-first q-tile permutation: per-CU work equalized, heavy dispatched first
  const int y = blockIdx.y;
  const int perm = (y < 4) ? (15 - y) : (y < 8) ? (y + 4) : (y < 12) ? (y - 4) : (15 - y);
  const int q0 = perm * 128;
  const int qw = q0 + wid * 32;          // wave covers q rows qw .. qw+31 (2 sets of 16)
  const _Float16* Qb = Q + (long)bh * SEQ * HD;
  const _Float16* Kb = K + (long)bh * SEQ * HD;
  const _Float16* Vb = Vt + (long)bh * HD * SEQ;

  half8 qf[2][2];
#pragma unroll
  for (int s = 0; s < 2; ++s) {
    qf[s][0] = *(const half8*)&Qb[(qw + s*16 + fr)*HD + fg*8];
    qf[s][1] = *(const half8*)&Qb[(qw + s*16 + fr)*HD + 32 + fg*8];
  }

  f32x4 oaccT[2][4] = {};
  float m_s[2] = { -1e30f, -1e30f }, l_s[2] = { 0.f, 0.f };

  const int srow = lane >> 3;                 // 0..7 (row within 8-row chunk)
  const int sc16 = (lane & 7) ^ srow;         // pre-swizzled source slot
  const int r1 = wid*16 + srow, r2 = r1 + 8;  // rows this wave stages

  char* Pb = (char*)&Ps[wid][0];
  const int swp = (fr & 7) << 4;              // P swizzle for this lane's q-row
  const int nt = q0/64 + 2;

  // prologue: stage tile 0 into buf 0
  gload16(Kb + (long)r1*HD + sc16*8, &Ks[0][(wid*16)*64]);
  gload16(Kb + (long)r2*HD + sc16*8, &Ks[0][(wid*16 + 8)*64]);
  gload16(Vb + (long)r1*SEQ + sc16*8, &Vs[0][(wid*16)*64]);
  gload16(Vb + (long)r2*SEQ + sc16*8, &Vs[0][(wid*16 + 8)*64]);
  __syncthreads();

  int cur = 0;
  for (int t = 0; t < nt; ++t) {
    const int kv0 = t * 64;

    // prefetch next tile (drained by end-of-tile barrier -> latency hidden)
    if (t + 1 < nt) {
      const int nkv = kv0 + 64;
      gload16(Kb + (long)(nkv + r1)*HD + sc16*8, &Ks[cur^1][(wid*16)*64]);
      gload16(Kb + (long)(nkv + r2)*HD + sc16*8, &Ks[cur^1][(wid*16 + 8)*64]);
      gload16(Vb + (long)r1*SEQ + nkv + sc16*8,  &Vs[cur^1][(wid*16)*64]);
      gload16(Vb + (long)r2*SEQ + nkv + sc16*8,  &Vs[cur^1][(wid*16 + 8)*64]);
    }

    const char* Kc = (const char*)&Ks[cur][0];
    const char* Vc = (const char*)&Vs[cur][0];

#pragma unroll
    for (int s = 0; s < 2; ++s) {
      const int qa = qw + s*16 + fr;          // this lane's absolute q row

      // S^T = K Q^T : lane fr = q, regs hold kv = n*16 + fg*4 + r
      f32x4 sa[4];
      __builtin_amdgcn_s_setprio(1);
#pragma unroll
      for (int n = 0; n < 4; ++n) {
        const int row = n*16 + fr;
        const int sw = (row & 7) << 4;
        const half8 k0v = *(const half8*)(Kc + row*128 + ((fg*16) ^ sw));
        const half8 k1v = *(const half8*)(Kc + row*128 + ((64 + fg*16) ^ sw));
        f32x4 z = {0.f, 0.f, 0.f, 0.f};
        z = __builtin_amdgcn_mfma_f32_16x16x32_f16(k0v, qf[s][0], z, 0, 0, 0);
        sa[n] = __builtin_amdgcn_mfma_f32_16x16x32_f16(k1v, qf[s][1], z, 0, 0, 0);
      }
      __builtin_amdgcn_s_setprio(0);

      if (kv0 + 63 > qw + s*16) {            // masked region for this set
#pragma unroll
        for (int n = 0; n < 4; ++n) {
          const int kvb = kv0 + n*16 + fg*4;
#pragma unroll
          for (int r = 0; r < 4; ++r)
            if (kvb + r > qa) sa[n][r] = -1e30f;
        }
      }

      // row max: in-lane 16 -> cross-fg (2 shuffles)
      float pm0 = fmaxf(fmaxf(sa[0][0], sa[0][1]), fmaxf(sa[0][2], sa[0][3]));
      float pm1 = fmaxf(fmaxf(sa[1][0], sa[1][1]), fmaxf(sa[1][2], sa[1][3]));
      float pm2 = fmaxf(fmaxf(sa[2][0], sa[2][1]), fmaxf(sa[2][2], sa[2][3]));
      float pm3 = fmaxf(fmaxf(sa[3][0], sa[3][1]), fmaxf(sa[3][2], sa[3][3]));
      float pm = fmaxf(fmaxf(pm0, pm1), fmaxf(pm2, pm3));
      pm = fmaxf(pm, __shfl_xor(pm, 16));
      pm = fmaxf(pm, __shfl_xor(pm, 32));

      const float mn = fmaxf(m_s[s], pm);
      const float fac = __expf(m_s[s] - mn);
      m_s[s] = mn;

      float ps = 0.f;
#pragma unroll
      for (int n = 0; n < 4; ++n)
#pragma unroll
        for (int r = 0; r < 4; ++r) {
          const float p = __expf(sa[n][r] - mn);
          sa[n][r] = p;
          ps += p;
        }
      ps += __shfl_xor(ps, 16);
      ps += __shfl_xor(ps, 32);
      l_s[s] = l_s[s]*fac + ps;

#pragma unroll
      for (int n = 0; n < 4; ++n) {
        oaccT[s][n][0] *= fac; oaccT[s][n][1] *= fac;
        oaccT[s][n][2] *= fac; oaccT[s][n][3] *= fac;
      }

      // P (row q=fr, kv-consecutive) -> packed b64 writes, XOR-swizzled
#pragma unroll
      for (int n = 0; n < 4; ++n) {
        half4 p4 = { (_Float16)sa[n][0], (_Float16)sa[n][1],
                     (_Float16)sa[n][2], (_Float16)sa[n][3] };
        *(half4*)(Pb + ((fr*128 + n*32 + fg*8) ^ swp)) = p4;
      }

      // O^T += V^T P^T : A = V^T frag (lane fr = d), B = P frag (lane fr = q)
      __builtin_amdgcn_s_setprio(1);
#pragma unroll
      for (int ks = 0; ks < 2; ++ks) {
        const half8 pf = *(const half8*)(Pb + ((fr*128 + ks*64 + fg*16) ^ swp));
#pragma unroll
        for (int nd = 0; nd < 4; ++nd) {
          const int row = nd*16 + fr;
          const int sw = (row & 7) << 4;
          const half8 vf = *(const half8*)(Vc + row*128 + ((ks*64 + fg*16) ^ sw));
          oaccT[s][nd] = __builtin_amdgcn_mfma_f32_16x16x32_f16(vf, pf, oaccT[s][nd], 0, 0, 0);
        }
      }
      __builtin_amdgcn_s_setprio(0);
    }

    __syncthreads();           // implicit vmcnt(0): prefetch drained; buffers swappable
    cur ^= 1;
  }

  // epilogue: O^T lane fr = q -> row-contiguous packed stores
#pragma unroll
  for (int s = 0; s < 2; ++s) {
    const float rl = __builtin_amdgcn_rcpf(l_s[s]);
    _Float16* orow = O + ((long)b*SEQ + (qw + s*16 + fr))*DM + h*64;
#pragma unroll
    for (int nd = 0; nd < 4; ++nd) {
      half4 o4 = { (_Float16)(oaccT[s][nd][0]*rl), (_Float16)(oaccT[s][nd][1]*rl),
                   (_Float16)(oaccT[s][nd][2]*rl), (_Float16)(oaccT[s][nd][3]*rl) };
      *(half4*)&orow[nd*16 + fg*4] = o4;
    }
  }
}

extern "C" void kernel_launch(void* const* d_in, const int* in_sizes, int n_in,
                              void* d_out, int out_size, void* d_ws, size_t ws_size,
                              hipStream_t stream) {
  const float* x  = (const float*)d_in[0];
  const float* Wq = (const float*)d_in[1];
  const float* Wk = (const float*)d_in[2];
  const float* Wv = (const float*)d_in[3];
  const float* Wo = (const float*)d_in[4];
  const int*   tp = (const int*)d_in[5];
  float* out = (float*)d_out;

  char* ws = (char*)d_ws;
  _Float16* xh   = (_Float16*)(ws);                  // 16 MB  [8192][1024]
  _Float16* Wqkv = (_Float16*)(ws + (16u << 20));    //  6 MB  [3072][1024]
  _Float16* Woh  = (_Float16*)(ws + (22u << 20));    //  2 MB  [1024][1024]
  _Float16* Qb   = (_Float16*)(ws + (24u << 20));    // 16 MB  [64][2048][64]
  _Float16* Kb   = (_Float16*)(ws + (40u << 20));    // 16 MB
  _Float16* Vtb  = (_Float16*)(ws + (56u << 20));    // 16 MB  [64][64][2048]
  _Float16* attn = (_Float16*)(ws + (72u << 20));    // 16 MB  [8192][1024]

  cvt4<<<8192, 256, 0, stream>>>(x,  xh, 2097152);
  cvt4<<<1024, 256, 0, stream>>>(Wq, Wqkv,               262144);
  cvt4<<<1024, 256, 0, stream>>>(Wk, Wqkv + (1u << 20),  262144);
  cvt4<<<1024, 256, 0, stream>>>(Wv, Wqkv + (2u << 20),  262144);
  cvt4<<<1024, 256, 0, stream>>>(Wo, Woh,                262144);

  gemm_hk<0><<<dim3(64, 24), 256, 0, stream>>>(xh, Wqkv, Qb, Kb, Vtb, nullptr);
  rope_k<<<dim3(256, 64, 2), 256, 0, stream>>>(Qb, Kb, tp);
  fattn<<<dim3(64, 16), 256, 0, stream>>>(Qb, Kb, Vtb, attn);
  gemm_hk<1><<<dim3(64, 8), 256, 0, stream>>>(attn, Woh, nullptr, nullptr, nullptr, out);
}